// Round 2
// baseline (105.223 us; speedup 1.0000x reference)
//
#include <hip/hip_runtime.h>
#include <hip/hip_cooperative_groups.h>

namespace cg = cooperative_groups;

// MPSLayer: out[b,o] = s_b * q[o] + bias[o]
//   s_b = prod_i x[b,i]
//   u^T = 1^T prod_i C_i   (16 segment products of 16 cores, then folded)
//   q[o] = sum_r u[r] * P2[r,o],  P2[r,o] = sum_l proj[r,l,o]
//
// Single cooperative kernel: phase 1 = segment products + P2 + s,
// grid.sync(), phase 2 = per-block redundant fold of u + output rows.
//
// ws layout (floats):
//   [0,     16384) : M_seg[16][32][32]   (row l, col c)
//   [16384, 32768) : P2[32][512]
//   [32768, 33792) : s[1024]

#define NSEG   16
#define SEGLEN 16
#define NBLK   (NSEG + 32 + 128)   // 176 blocks, <= co-resident capacity

__global__ __launch_bounds__(512) void mps_fused(const float* __restrict__ x,
                                                 const float* __restrict__ cores,
                                                 const float* __restrict__ proj,
                                                 const float* __restrict__ bias,
                                                 float* __restrict__ ws,
                                                 float* __restrict__ out) {
    __shared__ float smem[SEGLEN * 1024];   // 64 KB: Craw in phase 1, u_sh in phase 2
    const int blk = blockIdx.x;
    const int t   = threadIdx.x;

    // ================= phase 1 =================
    if (blk < NSEG) {
        // ---- role A: segment product M = C[16s] @ ... @ C[16s+15]
        // State in registers: thread (par,cg,l) holds M[l][cg*4 .. cg*4+3]
        // (replicated across par twins; par splits k into halves, combined
        // via shfl_xor(1)). Row l depends only on row l -> no barriers in
        // the 15-step chain.
        const float* cbase = cores + (size_t)blk * (SEGLEN * 1024);
        #pragma unroll
        for (int j = 0; j < 8; ++j) {
            int f = j * 2048 + t * 4;
            *(float4*)&smem[f] = *(const float4*)(cbase + f);
        }
        __syncthreads();

        const int par = t & 1;            // k-half: 0 -> k=0..15, 1 -> k=16..31
        const int c0  = ((t >> 1) & 7) << 2;
        const int l   = t >> 4;           // 0..31
        const int llo = (t >> 4) & 3;     // row within wave
        // holder of M[l][k]: lane (llo<<4) | ((k>>2)<<1) | par, register k&3.
        const int srcBase = (llo << 4) + par * 9;

        float4 ini = *(const float4*)&smem[l * 32 + c0];   // M = C_0
        float s0 = ini.x, s1 = ini.y, s2 = ini.z, s3 = ini.w;

        for (int i = 1; i < SEGLEN; ++i) {
            const float* Ci = &smem[i * 1024 + (par << 9)];  // rows 16*par ..
            float a0 = 0.f, a1 = 0.f, a2 = 0.f, a3 = 0.f;
            #pragma unroll
            for (int j = 0; j < 16; ++j) {
                const float sv = ((j & 3) == 0) ? s0
                               : ((j & 3) == 1) ? s1
                               : ((j & 3) == 2) ? s2 : s3;
                const float pv = __shfl(sv, srcBase + ((j >> 2) << 1), 64);
                const float4 cv = *(const float4*)&Ci[j * 32 + c0];
                a0 = fmaf(pv, cv.x, a0);
                a1 = fmaf(pv, cv.y, a1);
                a2 = fmaf(pv, cv.z, a2);
                a3 = fmaf(pv, cv.w, a3);
            }
            s0 = a0 + __shfl_xor(a0, 1, 64);
            s1 = a1 + __shfl_xor(a1, 1, 64);
            s2 = a2 + __shfl_xor(a2, 1, 64);
            s3 = a3 + __shfl_xor(a3, 1, 64);
        }
        if (par == 0)
            *(float4*)(ws + blk * 1024 + l * 32 + c0) = make_float4(s0, s1, s2, s3);

    } else if (blk < NSEG + 32) {
        // ---- role B: P2[r,o] = sum_l proj[r,l,o]
        const int e = (blk - NSEG) * 512 + t;
        const int r = e >> 9;
        const int o = e & 511;
        float s0 = 0.f, s1 = 0.f, s2 = 0.f, s3 = 0.f;
        #pragma unroll
        for (int l = 0; l < 32; l += 4) {
            s0 += proj[(size_t)(r * 32 + l) * 512 + o];
            s1 += proj[(size_t)(r * 32 + l + 1) * 512 + o];
            s2 += proj[(size_t)(r * 32 + l + 2) * 512 + o];
            s3 += proj[(size_t)(r * 32 + l + 3) * 512 + o];
        }
        ws[16384 + e] = (s0 + s1) + (s2 + s3);

    } else {
        // ---- role C: s[b] = prod_i x[b,i]; one 64-lane wave per batch row
        const int wave = t >> 6;
        const int lane = t & 63;
        const int b    = (blk - (NSEG + 32)) * 8 + wave;
        float4 v = *(const float4*)(x + (size_t)b * 256 + lane * 4);
        float p = v.x * v.y * v.z * v.w;
        #pragma unroll
        for (int off = 32; off >= 1; off >>= 1)
            p *= __shfl_xor(p, off, 64);
        if (lane == 0) ws[32768 + b] = p;
    }

    cg::this_grid().sync();

    // ================= phase 2: blocks 0..127 write 8 output rows each =====
    if (blk < 128) {
        const float* P2 = ws + 16384;
        float p[32];
        #pragma unroll
        for (int r = 0; r < 32; ++r) p[r] = P2[r * 512 + t];

        if (t < 64) {
            // fold u^T = 1^T M_0 ... M_15 from L2 (hot), u replicated in regs.
            const int h  = t >> 5;
            const int c  = t & 31;
            const int rb = h << 4;
            float cur[16];
            #pragma unroll
            for (int j = 0; j < 16; ++j) cur[j] = ws[(rb + j) * 32 + c];  // M0
            float a0 = 0.f, a1 = 0.f, a2 = 0.f, a3 = 0.f;
            #pragma unroll
            for (int j = 0; j < 16; j += 4) {
                a0 += cur[j]; a1 += cur[j + 1]; a2 += cur[j + 2]; a3 += cur[j + 3];
            }
            float u = (a0 + a1) + (a2 + a3);
            u += __shfl_xor(u, 32, 64);            // u = 1^T M0, replicated

            #pragma unroll
            for (int j = 0; j < 16; ++j) cur[j] = ws[1024 + (rb + j) * 32 + c];
            #pragma unroll
            for (int i = 1; i < 16; ++i) {
                float nxt[16];
                if (i < 15) {
                    #pragma unroll
                    for (int j = 0; j < 16; ++j)
                        nxt[j] = ws[(i + 1) * 1024 + (rb + j) * 32 + c];
                }
                float b0 = 0.f, b1 = 0.f, b2 = 0.f, b3 = 0.f;
                #pragma unroll
                for (int j = 0; j < 16; j += 4) {
                    b0 = fmaf(__shfl(u, rb + j,     64), cur[j],     b0);
                    b1 = fmaf(__shfl(u, rb + j + 1, 64), cur[j + 1], b1);
                    b2 = fmaf(__shfl(u, rb + j + 2, 64), cur[j + 2], b2);
                    b3 = fmaf(__shfl(u, rb + j + 3, 64), cur[j + 3], b3);
                }
                float un = (b0 + b1) + (b2 + b3);
                un += __shfl_xor(un, 32, 64);
                u = un;
                if (i < 15) {
                    #pragma unroll
                    for (int j = 0; j < 16; ++j) cur[j] = nxt[j];
                }
            }
            if (t < 32) smem[t] = u;               // u_sh
        }
        __syncthreads();

        float q0 = 0.f, q1 = 0.f, q2 = 0.f, q3 = 0.f;
        #pragma unroll
        for (int r = 0; r < 32; r += 4) {
            q0 = fmaf(smem[r],     p[r],     q0);
            q1 = fmaf(smem[r + 1], p[r + 1], q1);
            q2 = fmaf(smem[r + 2], p[r + 2], q2);
            q3 = fmaf(smem[r + 3], p[r + 3], q3);
        }
        const float qv = (q0 + q1) + (q2 + q3);
        const float bv = bias[t];

        const int b0i = blk * 8;
        #pragma unroll
        for (int j = 0; j < 8; ++j) {
            const float s = ws[32768 + b0i + j];
            out[(size_t)(b0i + j) * 512 + t] = fmaf(s, qv, bv);
        }
    }
}

extern "C" void kernel_launch(void* const* d_in, const int* in_sizes, int n_in,
                              void* d_out, int out_size, void* d_ws, size_t ws_size,
                              hipStream_t stream) {
    const float* x     = (const float*)d_in[0];   // [1024, 256]
    const float* cores = (const float*)d_in[1];   // [256, 32, 32]
    const float* proj  = (const float*)d_in[2];   // [32, 32, 512]
    const float* bias  = (const float*)d_in[3];   // [512]
    float* out = (float*)d_out;                    // [1024, 512]
    float* ws  = (float*)d_ws;

    void* args[] = {(void*)&x, (void*)&cores, (void*)&proj,
                    (void*)&bias, (void*)&ws, (void*)&out};
    hipLaunchCooperativeKernel((const void*)mps_fused, dim3(NBLK), dim3(512),
                               args, 0, stream);
}

// Round 3
// 89.023 us; speedup vs baseline: 1.1820x; 1.1820x over previous
//
#include <hip/hip_runtime.h>

// MPSLayer: out[b,o] = s_b * q[o] + bias[o]
//   s_b = prod_i x[b,i]                      (block-local: 8 rows/block)
//   u^T = 1^T prod_i C_i   (16 segment products of 16 cores, then folded)
//   q[o] = sum_r u[r] * P2[r,o],  P2[r,o] = sum_l proj[r,l,o]
//
// SINGLE regular launch, 128 blocks. Cross-block deps (M_seg, P2) are
// handled by a device-scope flag barrier: 48 producer blocks each publish a
// 2-word per-producer magic flag after __threadfence(); consumers
// acquire-spin on all 48. 128 blocks * 64.2KB LDS -> every block gets its
// own CU (128 < 256), so all workgroups are co-resident and the spin
// cannot deadlock. Two index-dependent magic words cannot collide with the
// harness's constant poison pattern; a stale flag from a previous
// iteration would only expose bit-identical recomputed data (inputs are
// constant), so correctness holds either way.
//
// ws layout (floats):
//   [0,     16384) : M_seg[16][32][32]   (row l, col c)
//   [16384, 32768) : P2[32][512]
//   [33792, 33888) : flags[48][2] (as uint32)

#define NSEG   16
#define SEGLEN 16
#define NBLK   128
#define NPROD  48

__device__ __forceinline__ unsigned fv0(int i) { return 0x5A17C3D2u ^ (0x01010101u * (unsigned)i); }
__device__ __forceinline__ unsigned fv1(int i) { return 0xA5E8143Bu + 0x9E3779B9u * (unsigned)i; }

__global__ __launch_bounds__(512) void mps_one(const float* __restrict__ x,
                                               const float* __restrict__ cores,
                                               const float* __restrict__ proj,
                                               const float* __restrict__ bias,
                                               float* __restrict__ ws,
                                               float* __restrict__ out) {
    __shared__ float smem[SEGLEN * 1024];   // 64 KB: Craw for role A blocks
    __shared__ float s_sh[8];
    __shared__ float u_sh[32];
    const int blk = blockIdx.x;
    const int t   = threadIdx.x;
    unsigned* flags = (unsigned*)(ws + 33792);

    // ---- role C (every block): s for the 8 rows this block will output
    {
        const int wave = t >> 6;
        const int lane = t & 63;
        const int b    = blk * 8 + wave;
        float4 v = *(const float4*)(x + (size_t)b * 256 + lane * 4);
        float p = v.x * v.y * v.z * v.w;
        #pragma unroll
        for (int off = 32; off >= 1; off >>= 1)
            p *= __shfl_xor(p, off, 64);
        if (lane == 0) s_sh[wave] = p;
    }

    if (blk < NSEG) {
        // ---- role A: segment product M = C[16s] @ ... @ C[16s+15]
        // State in registers; par twins split k-halves, combined via
        // shfl_xor(1); no barriers inside the 15-step chain.
        const float* cbase = cores + (size_t)blk * (SEGLEN * 1024);
        #pragma unroll
        for (int j = 0; j < 8; ++j) {
            int f = j * 2048 + t * 4;
            *(float4*)&smem[f] = *(const float4*)(cbase + f);
        }
        __syncthreads();

        const int par = t & 1;
        const int c0  = ((t >> 1) & 7) << 2;
        const int l   = t >> 4;
        const int llo = (t >> 4) & 3;
        const int srcBase = (llo << 4) + par * 9;

        float4 ini = *(const float4*)&smem[l * 32 + c0];   // M = C_0
        float s0 = ini.x, s1 = ini.y, s2 = ini.z, s3 = ini.w;

        for (int i = 1; i < SEGLEN; ++i) {
            const float* Ci = &smem[i * 1024 + (par << 9)];
            float a0 = 0.f, a1 = 0.f, a2 = 0.f, a3 = 0.f;
            #pragma unroll
            for (int j = 0; j < 16; ++j) {
                const float sv = ((j & 3) == 0) ? s0
                               : ((j & 3) == 1) ? s1
                               : ((j & 3) == 2) ? s2 : s3;
                const float pv = __shfl(sv, srcBase + ((j >> 2) << 1), 64);
                const float4 cv = *(const float4*)&Ci[j * 32 + c0];
                a0 = fmaf(pv, cv.x, a0);
                a1 = fmaf(pv, cv.y, a1);
                a2 = fmaf(pv, cv.z, a2);
                a3 = fmaf(pv, cv.w, a3);
            }
            s0 = a0 + __shfl_xor(a0, 1, 64);
            s1 = a1 + __shfl_xor(a1, 1, 64);
            s2 = a2 + __shfl_xor(a2, 1, 64);
            s3 = a3 + __shfl_xor(a3, 1, 64);
        }
        if (par == 0)
            *(float4*)(ws + blk * 1024 + l * 32 + c0) = make_float4(s0, s1, s2, s3);

        __syncthreads();               // drains all global stores (vmcnt 0)
        if (t == 0) {
            __threadfence();           // agent-scope release of M_seg
            __hip_atomic_store(&flags[2 * blk],     fv0(blk), __ATOMIC_RELEASE, __HIP_MEMORY_SCOPE_AGENT);
            __hip_atomic_store(&flags[2 * blk + 1], fv1(blk), __ATOMIC_RELEASE, __HIP_MEMORY_SCOPE_AGENT);
        }

    } else if (blk < NSEG + 32) {
        // ---- role B: P2[r,o] = sum_l proj[r,l,o]
        const int e = (blk - NSEG) * 512 + t;
        const int r = e >> 9;
        const int o = e & 511;
        float s0 = 0.f, s1 = 0.f, s2 = 0.f, s3 = 0.f;
        #pragma unroll
        for (int l = 0; l < 32; l += 4) {
            s0 += proj[(size_t)(r * 32 + l) * 512 + o];
            s1 += proj[(size_t)(r * 32 + l + 1) * 512 + o];
            s2 += proj[(size_t)(r * 32 + l + 2) * 512 + o];
            s3 += proj[(size_t)(r * 32 + l + 3) * 512 + o];
        }
        ws[16384 + e] = (s0 + s1) + (s2 + s3);

        __syncthreads();
        if (t == 0) {
            __threadfence();
            __hip_atomic_store(&flags[2 * blk],     fv0(blk), __ATOMIC_RELEASE, __HIP_MEMORY_SCOPE_AGENT);
            __hip_atomic_store(&flags[2 * blk + 1], fv1(blk), __ATOMIC_RELEASE, __HIP_MEMORY_SCOPE_AGENT);
        }
    }

    // ---- flag barrier: wait for all 48 producers
    if (t < NPROD) {
        const unsigned v0 = fv0(t), v1 = fv1(t);
        while (__hip_atomic_load(&flags[2 * t], __ATOMIC_ACQUIRE, __HIP_MEMORY_SCOPE_AGENT) != v0 ||
               __hip_atomic_load(&flags[2 * t + 1], __ATOMIC_ACQUIRE, __HIP_MEMORY_SCOPE_AGENT) != v1)
            __builtin_amdgcn_s_sleep(8);
        __threadfence();               // acquire: invalidate stale cache lines
    }
    __syncthreads();

    // ---- phase 2: fold u, compute q, write 8 output rows
    const float* P2 = ws + 16384;
    float p[32];
    #pragma unroll
    for (int r = 0; r < 32; ++r) p[r] = P2[r * 512 + t];

    if (t < 64) {
        // fold u^T = 1^T M_0 ... M_15 from L2 (hot), u replicated in regs.
        const int h  = t >> 5;
        const int c  = t & 31;
        const int rb = h << 4;
        float cur[16];
        #pragma unroll
        for (int j = 0; j < 16; ++j) cur[j] = ws[(rb + j) * 32 + c];  // M0
        float a0 = 0.f, a1 = 0.f, a2 = 0.f, a3 = 0.f;
        #pragma unroll
        for (int j = 0; j < 16; j += 4) {
            a0 += cur[j]; a1 += cur[j + 1]; a2 += cur[j + 2]; a3 += cur[j + 3];
        }
        float u = (a0 + a1) + (a2 + a3);
        u += __shfl_xor(u, 32, 64);            // u = 1^T M0, replicated

        #pragma unroll
        for (int j = 0; j < 16; ++j) cur[j] = ws[1024 + (rb + j) * 32 + c];
        #pragma unroll
        for (int i = 1; i < 16; ++i) {
            float nxt[16];
            if (i < 15) {
                #pragma unroll
                for (int j = 0; j < 16; ++j)
                    nxt[j] = ws[(i + 1) * 1024 + (rb + j) * 32 + c];
            }
            float b0 = 0.f, b1 = 0.f, b2 = 0.f, b3 = 0.f;
            #pragma unroll
            for (int j = 0; j < 16; j += 4) {
                b0 = fmaf(__shfl(u, rb + j,     64), cur[j],     b0);
                b1 = fmaf(__shfl(u, rb + j + 1, 64), cur[j + 1], b1);
                b2 = fmaf(__shfl(u, rb + j + 2, 64), cur[j + 2], b2);
                b3 = fmaf(__shfl(u, rb + j + 3, 64), cur[j + 3], b3);
            }
            float un = (b0 + b1) + (b2 + b3);
            un += __shfl_xor(un, 32, 64);
            u = un;
            if (i < 15) {
                #pragma unroll
                for (int j = 0; j < 16; ++j) cur[j] = nxt[j];
            }
        }
        if (t < 32) u_sh[t] = u;
    }
    __syncthreads();

    float q0 = 0.f, q1 = 0.f, q2 = 0.f, q3 = 0.f;
    #pragma unroll
    for (int r = 0; r < 32; r += 4) {
        q0 = fmaf(u_sh[r],     p[r],     q0);
        q1 = fmaf(u_sh[r + 1], p[r + 1], q1);
        q2 = fmaf(u_sh[r + 2], p[r + 2], q2);
        q3 = fmaf(u_sh[r + 3], p[r + 3], q3);
    }
    const float qv = (q0 + q1) + (q2 + q3);
    const float bv = bias[t];

    const int b0i = blk * 8;
    #pragma unroll
    for (int j = 0; j < 8; ++j) {
        out[(size_t)(b0i + j) * 512 + t] = fmaf(s_sh[j], qv, bv);
    }
}

extern "C" void kernel_launch(void* const* d_in, const int* in_sizes, int n_in,
                              void* d_out, int out_size, void* d_ws, size_t ws_size,
                              hipStream_t stream) {
    const float* x     = (const float*)d_in[0];   // [1024, 256]
    const float* cores = (const float*)d_in[1];   // [256, 32, 32]
    const float* proj  = (const float*)d_in[2];   // [32, 32, 512]
    const float* bias  = (const float*)d_in[3];   // [512]
    float* out = (float*)d_out;                    // [1024, 512]
    float* ws  = (float*)d_ws;

    hipLaunchKernelGGL(mps_one, dim3(NBLK), dim3(512), 0, stream,
                       x, cores, proj, bias, ws, out);
}

// Round 4
// 79.268 us; speedup vs baseline: 1.3274x; 1.1231x over previous
//
#include <hip/hip_runtime.h>

// MPSLayer: out[b,o] = s_b * q[o] + bias[o]
//   s_b = prod_i x[b,i]
//   u^T = 1^T prod_i C_i   (16 segment products of 16 cores, then folded)
//   q[o] = sum_r u[r] * P2[r,o],  P2[r,o] = sum_l proj[r,l,o]
//
// Best verified structure (79.2 us): two plain launches. Measured facts:
//  - cooperative grid.sync() launch: +26 us (round 2)
//  - single launch + device-scope flag barrier: +10 us (round 3, cross-XCD
//    fence/invalidate + remote-L2 reads cost more than a dispatch boundary)
//  - the timed window is dominated by the harness's 256 MiB poison fill
//    (40.5 us @ 83% HBM peak) + reset dispatch swarm; kernel side is ~10 us.
//
// ws layout (floats):
//   [0,     16384) : M_seg[16][32][32]   (row l, col c)
//   [16384, 32768) : P2[32][512]
//   [32768, 33792) : s[1024]

#define NSEG   16
#define SEGLEN 16

__global__ __launch_bounds__(512) void mps_k1(const float* __restrict__ x,
                                              const float* __restrict__ cores,
                                              const float* __restrict__ proj,
                                              float* __restrict__ ws) {
    const int blk = blockIdx.x;
    const int t   = threadIdx.x;

    if (blk < NSEG) {
        // ---- role A: segment product M = C[16s] @ ... @ C[16s+15]
        // State held in REGISTERS: thread (par,cg,l) holds M[l][cg*4 .. cg*4+3]
        // (replicated across the par twins). par splits the k-reduction into
        // halves k=0..15 / k=16..31; twins combine via shfl_xor(1).
        // Row l depends only on row l -> each wave owns 4 rows, NO barriers
        // inside the 15-step chain.
        __shared__ float Craw[SEGLEN * 1024];
        const float* cbase = cores + (size_t)blk * (SEGLEN * 1024);
        #pragma unroll
        for (int j = 0; j < 8; ++j) {
            int f = j * 2048 + t * 4;
            *(float4*)&Craw[f] = *(const float4*)(cbase + f);
        }
        __syncthreads();

        const int par = t & 1;            // k-half: 0 -> k=0..15, 1 -> k=16..31
        const int cg  = (t >> 1) & 7;     // column group (4 cols)
        const int c0  = cg << 2;
        const int l   = t >> 4;           // 0..31 (4 rows per wave)
        const int llo = (t >> 4) & 3;     // row within wave
        // holder of M[l][k]: lane (llo<<4) | ((k>>2)<<1) | par, register k&3.
        // k = 16*par + j  ->  srcLane = llo*16 + 9*par + 2*(j>>2)
        const int srcBase = (llo << 4) + par * 9;

        float4 ini = *(const float4*)&Craw[l * 32 + c0];   // M = C_0
        float s0 = ini.x, s1 = ini.y, s2 = ini.z, s3 = ini.w;

        for (int i = 1; i < SEGLEN; ++i) {
            const float* Ci = &Craw[i * 1024 + (par << 9)];  // rows 16*par ..
            float a0 = 0.f, a1 = 0.f, a2 = 0.f, a3 = 0.f;
            #pragma unroll
            for (int j = 0; j < 16; ++j) {
                const float sv = ((j & 3) == 0) ? s0
                               : ((j & 3) == 1) ? s1
                               : ((j & 3) == 2) ? s2 : s3;
                const float pv = __shfl(sv, srcBase + ((j >> 2) << 1), 64);
                const float4 cv = *(const float4*)&Ci[j * 32 + c0];
                a0 = fmaf(pv, cv.x, a0);
                a1 = fmaf(pv, cv.y, a1);
                a2 = fmaf(pv, cv.z, a2);
                a3 = fmaf(pv, cv.w, a3);
            }
            // combine k-halves across the par twins (lanes differ in bit 0)
            s0 = a0 + __shfl_xor(a0, 1, 64);
            s1 = a1 + __shfl_xor(a1, 1, 64);
            s2 = a2 + __shfl_xor(a2, 1, 64);
            s3 = a3 + __shfl_xor(a3, 1, 64);
        }
        if (par == 0)
            *(float4*)(ws + blk * 1024 + l * 32 + c0) = make_float4(s0, s1, s2, s3);

    } else if (blk < NSEG + 32) {
        // ---- role B: P2[r,o] = sum_l proj[r,l,o]
        const int e = (blk - NSEG) * 512 + t;
        const int r = e >> 9;
        const int o = e & 511;
        float s0 = 0.f, s1 = 0.f, s2 = 0.f, s3 = 0.f;
        #pragma unroll
        for (int l = 0; l < 32; l += 4) {
            s0 += proj[(size_t)(r * 32 + l) * 512 + o];
            s1 += proj[(size_t)(r * 32 + l + 1) * 512 + o];
            s2 += proj[(size_t)(r * 32 + l + 2) * 512 + o];
            s3 += proj[(size_t)(r * 32 + l + 3) * 512 + o];
        }
        ws[16384 + e] = (s0 + s1) + (s2 + s3);

    } else {
        // ---- role C: s[b] = prod_i x[b,i]; one 64-lane wave per batch row
        const int wave = t >> 6;
        const int lane = t & 63;
        const int b    = (blk - (NSEG + 32)) * 8 + wave;
        float4 v = *(const float4*)(x + (size_t)b * 256 + lane * 4);
        float p = v.x * v.y * v.z * v.w;
        #pragma unroll
        for (int off = 32; off >= 1; off >>= 1)
            p *= __shfl_xor(p, off, 64);
        if (lane == 0) ws[32768 + b] = p;
    }
}

__global__ __launch_bounds__(512) void mps_k2(const float* __restrict__ ws,
                                              const float* __restrict__ bias,
                                              float* __restrict__ out) {
    __shared__ float u_sh[32];
    const int t = threadIdx.x;
    const float* P2 = ws + 16384;

    // issue P2 loads early (all waves) -> latency hides under the fold
    float p[32];
    #pragma unroll
    for (int r = 0; r < 32; ++r) p[r] = P2[r * 512 + t];

    if (t < 64) {
        // fold u^T = 1^T M_0 ... M_15 straight from L2, u replicated in regs.
        // halves: lanes 0-31 rows 0..15, lanes 32-63 rows 16..31.
        const int h  = t >> 5;
        const int c  = t & 31;
        const int rb = h << 4;                 // 16*h
        float cur[16];
        #pragma unroll
        for (int j = 0; j < 16; ++j) cur[j] = ws[(rb + j) * 32 + c];  // M0
        float a0 = 0.f, a1 = 0.f, a2 = 0.f, a3 = 0.f;
        #pragma unroll
        for (int j = 0; j < 16; j += 4) {
            a0 += cur[j]; a1 += cur[j + 1]; a2 += cur[j + 2]; a3 += cur[j + 3];
        }
        float u = (a0 + a1) + (a2 + a3);
        u += __shfl_xor(u, 32, 64);            // u = 1^T M0, replicated

        #pragma unroll
        for (int j = 0; j < 16; ++j) cur[j] = ws[1024 + (rb + j) * 32 + c];  // M1
        #pragma unroll
        for (int i = 1; i < 16; ++i) {
            float nxt[16];
            if (i < 15) {                      // prefetch M_{i+1}
                #pragma unroll
                for (int j = 0; j < 16; ++j)
                    nxt[j] = ws[(i + 1) * 1024 + (rb + j) * 32 + c];
            }
            float b0 = 0.f, b1 = 0.f, b2 = 0.f, b3 = 0.f;
            #pragma unroll
            for (int j = 0; j < 16; j += 4) {
                b0 = fmaf(__shfl(u, rb + j,     64), cur[j],     b0);
                b1 = fmaf(__shfl(u, rb + j + 1, 64), cur[j + 1], b1);
                b2 = fmaf(__shfl(u, rb + j + 2, 64), cur[j + 2], b2);
                b3 = fmaf(__shfl(u, rb + j + 3, 64), cur[j + 3], b3);
            }
            float un = (b0 + b1) + (b2 + b3);
            un += __shfl_xor(un, 32, 64);
            u = un;
            if (i < 15) {
                #pragma unroll
                for (int j = 0; j < 16; ++j) cur[j] = nxt[j];
            }
        }
        if (t < 32) u_sh[t] = u;
    }
    __syncthreads();

    // q[t] = sum_r u[r] * P2[r,t]; then 8 output rows per block
    float q0 = 0.f, q1 = 0.f, q2 = 0.f, q3 = 0.f;
    #pragma unroll
    for (int r = 0; r < 32; r += 4) {
        q0 = fmaf(u_sh[r],     p[r],     q0);
        q1 = fmaf(u_sh[r + 1], p[r + 1], q1);
        q2 = fmaf(u_sh[r + 2], p[r + 2], q2);
        q3 = fmaf(u_sh[r + 3], p[r + 3], q3);
    }
    const float qv = (q0 + q1) + (q2 + q3);
    const float bv = bias[t];

    const int b0i = blockIdx.x * 8;
    #pragma unroll
    for (int j = 0; j < 8; ++j) {
        const float s = ws[32768 + b0i + j];
        out[(size_t)(b0i + j) * 512 + t] = fmaf(s, qv, bv);
    }
}

extern "C" void kernel_launch(void* const* d_in, const int* in_sizes, int n_in,
                              void* d_out, int out_size, void* d_ws, size_t ws_size,
                              hipStream_t stream) {
    const float* x     = (const float*)d_in[0];   // [1024, 256]
    const float* cores = (const float*)d_in[1];   // [256, 32, 32]
    const float* proj  = (const float*)d_in[2];   // [32, 32, 512]
    const float* bias  = (const float*)d_in[3];   // [512]
    float* out = (float*)d_out;                    // [1024, 512]
    float* ws  = (float*)d_ws;

    hipLaunchKernelGGL(mps_k1, dim3(NSEG + 32 + 128), dim3(512), 0, stream,
                       x, cores, proj, ws);
    hipLaunchKernelGGL(mps_k2, dim3(128), dim3(512), 0, stream, ws, bias, out);
}